// Round 1
// baseline (463.578 us; speedup 1.0000x reference)
//
#include <hip/hip_runtime.h>

#define NN 50000
#define NE 600000
#define DD 128
#define NG 64

// ---------------- setup kernels ----------------

__global__ void k_init(int* deg, int* fill) {
    int i = blockIdx.x * 256 + threadIdx.x;
    if (i < NN) { deg[i] = 1; fill[i] = 0; }   // deg starts at 1 (self-loop)
}

__global__ void k_hist(const int* __restrict__ dstv, int* __restrict__ deg) {
    int e = blockIdx.x * 256 + threadIdx.x;
    if (e < NE) atomicAdd(&deg[dstv[e]], 1);
}

// block-level inclusive scan -> exclusive row_ptr pieces + block sums; also dinv = rsqrt(deg)
__global__ void k_scan1(const int* __restrict__ deg, float* __restrict__ dinv,
                        int* __restrict__ rp, int* __restrict__ bsum) {
    __shared__ int s[256];
    int t = threadIdx.x, i = blockIdx.x * 256 + t;
    int v = (i < NN) ? deg[i] : 0;
    if (i < NN) dinv[i] = rsqrtf((float)v);
    s[t] = v; __syncthreads();
    for (int off = 1; off < 256; off <<= 1) {
        int x = (t >= off) ? s[t - off] : 0;
        __syncthreads();
        s[t] += x;
        __syncthreads();
    }
    if (i < NN) rp[i] = s[t] - v;           // exclusive
    if (t == 255) bsum[blockIdx.x] = s[255];
}

__global__ void k_scan2(int* bs, int nb) {  // in-place exclusive scan of block sums (nb <= 256)
    __shared__ int s[256];
    int t = threadIdx.x;
    int v = (t < nb) ? bs[t] : 0;
    s[t] = v; __syncthreads();
    for (int off = 1; off < 256; off <<= 1) {
        int x = (t >= off) ? s[t - off] : 0;
        __syncthreads();
        s[t] += x;
        __syncthreads();
    }
    if (t < nb) bs[t] = s[t] - v;
}

__global__ void k_scan3(int* rp, const int* bs) {
    int i = blockIdx.x * 256 + threadIdx.x;
    if (i < NN) rp[i] += bs[i >> 8];
    if (i == 0) rp[NN] = NE + NN;
}

// scatter edges (and self-loops) into CSR grouped by dst; col holds src ids
__global__ void k_scatter(const int* __restrict__ srcv, const int* __restrict__ dstv,
                          const int* __restrict__ rp, int* __restrict__ fill,
                          int* __restrict__ col) {
    int t = blockIdx.x * 256 + threadIdx.x;
    if (t < NE) {
        int s = srcv[t], d = dstv[t];
        int pos = rp[d] + atomicAdd(&fill[d], 1);
        col[pos] = s;
    } else if (t < NE + NN) {
        int i = t - NE;
        int pos = rp[i] + atomicAdd(&fill[i], 1);
        col[pos] = i;
    }
}

// ---------------- compute kernels ----------------

// out[r][c] = (X[r][:] @ W[:][c]) * dinv[r]   (hs = H * D^-1/2, scaled by source-side dinv)
// block: 256 threads, tile 64 rows x 64 cols, per-thread 8 rows x 2 cols
__global__ __launch_bounds__(256) void k_gemm(const float* __restrict__ X,
                                              const float* __restrict__ W,
                                              const float* __restrict__ dinv,
                                              float* __restrict__ out) {
    __shared__ float Wl[DD * 64];  // [k][c] 128x64
    __shared__ float Xl[64 * DD];  // [r][k] 64x128
    const int t = threadIdx.x;
    const int row0 = blockIdx.x * 64;
    const int c0 = blockIdx.y * 64;

    #pragma unroll
    for (int m = 0; m < 8; ++m) {          // 2048 float4 = W tile
        int v = m * 256 + t;
        int k = v >> 4, c4 = (v & 15) * 4;
        *(float4*)&Wl[k * 64 + c4] = *(const float4*)&W[k * DD + c0 + c4];
    }
    #pragma unroll
    for (int m = 0; m < 8; ++m) {          // 2048 float4 = X tile
        int v = m * 256 + t;
        int r = v >> 5, k4 = (v & 31) * 4;
        size_t gr = (size_t)(row0 + r);
        float4 val = make_float4(0.f, 0.f, 0.f, 0.f);
        if (gr < NN) val = *(const float4*)&X[gr * DD + k4];
        *(float4*)&Xl[r * DD + k4] = val;
    }
    __syncthreads();

    const int jc = t & 31, rg = t >> 5;
    float acc[8][2];
    #pragma unroll
    for (int i = 0; i < 8; ++i) { acc[i][0] = 0.f; acc[i][1] = 0.f; }

    const float* xbase = &Xl[rg * 8 * DD];
    for (int k = 0; k < DD; k += 4) {
        float2 w0 = *(float2*)&Wl[(k + 0) * 64 + jc * 2];
        float2 w1 = *(float2*)&Wl[(k + 1) * 64 + jc * 2];
        float2 w2 = *(float2*)&Wl[(k + 2) * 64 + jc * 2];
        float2 w3 = *(float2*)&Wl[(k + 3) * 64 + jc * 2];
        #pragma unroll
        for (int i = 0; i < 8; ++i) {
            float4 a = *(float4*)&xbase[i * DD + k];
            acc[i][0] += a.x * w0.x + a.y * w1.x + a.z * w2.x + a.w * w3.x;
            acc[i][1] += a.x * w0.y + a.y * w1.y + a.z * w2.y + a.w * w3.y;
        }
    }

    #pragma unroll
    for (int i = 0; i < 8; ++i) {
        size_t r = (size_t)(row0 + rg * 8 + i);
        if (r < NN) {
            float s = dinv[r];
            float2 o; o.x = acc[i][0] * s; o.y = acc[i][1] * s;
            *(float2*)&out[r * DD + c0 + jc * 2] = o;
        }
    }
}

// out[i] = maybe_relu( dinv[i] * sum_{p in row i} hs[col[p]] + bias )
// one wave per node; lane handles float2 of the 128-dim feature
__global__ __launch_bounds__(256) void k_agg(const float* __restrict__ hs,
                                             const int* __restrict__ col,
                                             const int* __restrict__ rp,
                                             const float* __restrict__ dinv,
                                             const float* __restrict__ bias,
                                             float* __restrict__ out, int relu) {
    int w = threadIdx.x >> 6, lane = threadIdx.x & 63;
    int i = blockIdx.x * 4 + w;
    if (i >= NN) return;
    int p0 = rp[i], p1 = rp[i + 1];
    int d = lane * 2;
    float ax = 0.f, ay = 0.f, bx = 0.f, by = 0.f;
    int p = p0;
    for (; p + 2 <= p1; p += 2) {
        int c0 = col[p], c1 = col[p + 1];
        float2 v0 = *(const float2*)(hs + (size_t)c0 * DD + d);
        float2 v1 = *(const float2*)(hs + (size_t)c1 * DD + d);
        ax += v0.x; ay += v0.y; bx += v1.x; by += v1.y;
    }
    if (p < p1) {
        int c = col[p];
        float2 v = *(const float2*)(hs + (size_t)c * DD + d);
        ax += v.x; ay += v.y;
    }
    ax += bx; ay += by;
    float s = dinv[i];
    float2 bb = *(const float2*)(bias + d);
    float ox = fmaf(s, ax, bb.x), oy = fmaf(s, ay, bb.y);
    if (relu) { ox = fmaxf(ox, 0.f); oy = fmaxf(oy, 0.f); }
    float2 o; o.x = ox; o.y = oy;
    *(float2*)(out + (size_t)i * DD + d) = o;
}

// batch is sorted: run-length accumulate per 128-node chunk, one atomic per (graph,dim) transition
__global__ void k_pool(const float* __restrict__ h, const int* __restrict__ batch,
                       float* __restrict__ sums, float* __restrict__ cnt) {
    int d = threadIdx.x;  // 0..127
    int start = blockIdx.x * 128;
    if (start >= NN) return;
    int end = min(start + 128, NN);
    float acc = 0.f, c = 0.f;
    int g = batch[start];
    for (int i = start; i < end; ++i) {
        int gi = batch[i];
        if (gi != g) {
            atomicAdd(&sums[g * DD + d], acc);
            if (d == 0) atomicAdd(&cnt[g], c);
            acc = 0.f; c = 0.f; g = gi;
        }
        acc += h[(size_t)i * DD + d];
        c += 1.f;
    }
    atomicAdd(&sums[g * DD + d], acc);
    if (d == 0) atomicAdd(&cnt[g], c);
}

__global__ void k_final(const float* __restrict__ sums, const float* __restrict__ cnt,
                        float* __restrict__ out) {
    int i = blockIdx.x * 256 + threadIdx.x;  // < NG*DD = 8192
    int g = i >> 7;
    out[i] = sums[i] / fmaxf(cnt[g], 1.f);
}

// ---------------- launch ----------------

extern "C" void kernel_launch(void* const* d_in, const int* in_sizes, int n_in,
                              void* d_out, int out_size, void* d_ws, size_t ws_size,
                              hipStream_t stream) {
    (void)in_sizes; (void)n_in; (void)out_size; (void)ws_size;
    const float* x  = (const float*)d_in[0];
    const int*   ei = (const int*)d_in[1];     // [2][NE], JAX x64-disabled -> int32
    const int*   bt = (const int*)d_in[2];
    const float* W1 = (const float*)d_in[3];
    const float* b1 = (const float*)d_in[4];
    const float* W2 = (const float*)d_in[5];
    const float* b2 = (const float*)d_in[6];
    const float* W3 = (const float*)d_in[7];
    const float* b3 = (const float*)d_in[8];
    float* out = (float*)d_out;
    char* ws = (char*)d_ws;

    size_t o = 0;
    auto alloc = [&](size_t bytes) { size_t r = o; o = (o + bytes + 511) & ~(size_t)511; return r; };
    int*   deg  = (int*)(ws + alloc((size_t)NN * 4));
    int*   fill = (int*)(ws + alloc((size_t)NN * 4));
    float* dinv = (float*)(ws + alloc((size_t)NN * 4));
    int*   rp   = (int*)(ws + alloc((size_t)(NN + 1) * 4));
    int*   bs   = (int*)(ws + alloc(256 * 4));
    int*   col  = (int*)(ws + alloc((size_t)(NE + NN) * 4));
    float* bufA = (float*)(ws + alloc((size_t)NN * DD * 4));
    float* bufB = (float*)(ws + alloc((size_t)NN * DD * 4));
    float* pool = (float*)(ws + alloc((size_t)(NG * DD + NG) * 4));
    float* cnt  = pool + NG * DD;

    const int* srcv = ei;        // edge_index[0]
    const int* dstv = ei + NE;   // edge_index[1]

    hipMemsetAsync(pool, 0, (size_t)(NG * DD + NG) * 4, stream);

    k_init<<<196, 256, 0, stream>>>(deg, fill);
    k_hist<<<(NE + 255) / 256, 256, 0, stream>>>(dstv, deg);
    k_scan1<<<196, 256, 0, stream>>>(deg, dinv, rp, bs);
    k_scan2<<<1, 256, 0, stream>>>(bs, 196);
    k_scan3<<<196, 256, 0, stream>>>(rp, bs);
    k_scatter<<<(NE + NN + 255) / 256, 256, 0, stream>>>(srcv, dstv, rp, fill, col);

    dim3 gg(782, 2);
    k_gemm<<<gg, 256, 0, stream>>>(x,    W1, dinv, bufA);
    k_agg<<<12500, 256, 0, stream>>>(bufA, col, rp, dinv, b1, bufB, 1);
    k_gemm<<<gg, 256, 0, stream>>>(bufB, W2, dinv, bufA);
    k_agg<<<12500, 256, 0, stream>>>(bufA, col, rp, dinv, b2, bufB, 1);
    k_gemm<<<gg, 256, 0, stream>>>(bufB, W3, dinv, bufA);
    k_agg<<<12500, 256, 0, stream>>>(bufA, col, rp, dinv, b3, bufB, 0);

    k_pool<<<(NN + 127) / 128, 128, 0, stream>>>(bufB, bt, pool, cnt);
    k_final<<<(NG * DD) / 256, 256, 0, stream>>>(pool, cnt, out);
}

// Round 2
// 406.160 us; speedup vs baseline: 1.1414x; 1.1414x over previous
//
#include <hip/hip_runtime.h>

#define NN 50000
#define NE 600000
#define DD 128
#define NG 64

typedef unsigned int uint;
typedef unsigned short ushort;

// ---------------- bf16 helpers ----------------

__device__ __forceinline__ float bf_lo(uint v) { return __uint_as_float(v << 16); }
__device__ __forceinline__ float bf_hi(uint v) { return __uint_as_float(v & 0xffff0000u); }
__device__ __forceinline__ ushort f2bf(float f) {
    uint u = __float_as_uint(f);
    uint r = (u + 0x7fffu + ((u >> 16) & 1u)) >> 16;   // round-nearest-even
    return (ushort)r;
}

// ---------------- setup kernels ----------------

__global__ void k_init(int* deg, int* fill) {
    int i = blockIdx.x * 256 + threadIdx.x;
    if (i < NN) { deg[i] = 1; fill[i] = 0; }   // deg starts at 1 (self-loop)
}

__global__ void k_hist(const int* __restrict__ dstv, int* __restrict__ deg) {
    int e = blockIdx.x * 256 + threadIdx.x;
    if (e < NE) atomicAdd(&deg[dstv[e]], 1);
}

__global__ void k_scan1(const int* __restrict__ deg, float* __restrict__ dinv,
                        int* __restrict__ rp, int* __restrict__ bsum) {
    __shared__ int s[256];
    int t = threadIdx.x, i = blockIdx.x * 256 + t;
    int v = (i < NN) ? deg[i] : 0;
    if (i < NN) dinv[i] = rsqrtf((float)v);
    s[t] = v; __syncthreads();
    for (int off = 1; off < 256; off <<= 1) {
        int x = (t >= off) ? s[t - off] : 0;
        __syncthreads();
        s[t] += x;
        __syncthreads();
    }
    if (i < NN) rp[i] = s[t] - v;           // exclusive
    if (t == 255) bsum[blockIdx.x] = s[255];
}

__global__ void k_scan2(int* bs, int nb) {
    __shared__ int s[256];
    int t = threadIdx.x;
    int v = (t < nb) ? bs[t] : 0;
    s[t] = v; __syncthreads();
    for (int off = 1; off < 256; off <<= 1) {
        int x = (t >= off) ? s[t - off] : 0;
        __syncthreads();
        s[t] += x;
        __syncthreads();
    }
    if (t < nb) bs[t] = s[t] - v;
}

__global__ void k_scan3(int* rp, const int* bs) {
    int i = blockIdx.x * 256 + threadIdx.x;
    if (i < NN) rp[i] += bs[i >> 8];
    if (i == 0) rp[NN] = NE + NN;
}

__global__ void k_scatter(const int* __restrict__ srcv, const int* __restrict__ dstv,
                          const int* __restrict__ rp, int* __restrict__ fill,
                          int* __restrict__ col) {
    int t = blockIdx.x * 256 + threadIdx.x;
    if (t < NE) {
        int s = srcv[t], d = dstv[t];
        int pos = rp[d] + atomicAdd(&fill[d], 1);
        col[pos] = s;
    } else if (t < NE + NN) {
        int i = t - NE;
        int pos = rp[i] + atomicAdd(&fill[i], 1);
        col[pos] = i;
    }
}

// ---------------- compute kernels ----------------

// out[r][c] = (X[r][:] @ W[:][c]) * dinv[r], written as bf16 gather table.
// INBF16: X is a bf16 table (layers 2,3); else fp32 (layer 1 input x).
template <int INBF16>
__global__ __launch_bounds__(256) void k_gemm(const void* __restrict__ Xv,
                                              const float* __restrict__ W,
                                              const float* __restrict__ dinv,
                                              ushort* __restrict__ out) {
    __shared__ float Wl[DD * 64];  // [k][c] 128x64
    __shared__ float Xl[64 * DD];  // [r][k] 64x128
    const int t = threadIdx.x;
    const int row0 = blockIdx.x * 64;
    const int c0 = blockIdx.y * 64;

    #pragma unroll
    for (int m = 0; m < 8; ++m) {          // W tile (fp32 always)
        int v = m * 256 + t;
        int k = v >> 4, c4 = (v & 15) * 4;
        *(float4*)&Wl[k * 64 + c4] = *(const float4*)&W[k * DD + c0 + c4];
    }
    #pragma unroll
    for (int m = 0; m < 8; ++m) {          // X tile -> fp32 in LDS
        int v = m * 256 + t;
        int r = v >> 5, k4 = (v & 31) * 4;
        size_t gr = (size_t)(row0 + r);
        float4 val = make_float4(0.f, 0.f, 0.f, 0.f);
        if (gr < NN) {
            if (INBF16) {
                uint2 p = *(const uint2*)((const ushort*)Xv + gr * DD + k4);
                val = make_float4(bf_lo(p.x), bf_hi(p.x), bf_lo(p.y), bf_hi(p.y));
            } else {
                val = *(const float4*)((const float*)Xv + gr * DD + k4);
            }
        }
        *(float4*)&Xl[r * DD + k4] = val;
    }
    __syncthreads();

    const int jc = t & 31, rg = t >> 5;
    float acc[8][2];
    #pragma unroll
    for (int i = 0; i < 8; ++i) { acc[i][0] = 0.f; acc[i][1] = 0.f; }

    const float* xbase = &Xl[rg * 8 * DD];
    for (int k = 0; k < DD; k += 4) {
        float2 w0 = *(float2*)&Wl[(k + 0) * 64 + jc * 2];
        float2 w1 = *(float2*)&Wl[(k + 1) * 64 + jc * 2];
        float2 w2 = *(float2*)&Wl[(k + 2) * 64 + jc * 2];
        float2 w3 = *(float2*)&Wl[(k + 3) * 64 + jc * 2];
        #pragma unroll
        for (int i = 0; i < 8; ++i) {
            float4 a = *(float4*)&xbase[i * DD + k];
            acc[i][0] += a.x * w0.x + a.y * w1.x + a.z * w2.x + a.w * w3.x;
            acc[i][1] += a.x * w0.y + a.y * w1.y + a.z * w2.y + a.w * w3.y;
        }
    }

    #pragma unroll
    for (int i = 0; i < 8; ++i) {
        size_t r = (size_t)(row0 + rg * 8 + i);
        if (r < NN) {
            float s = dinv[r];
            ushort2 o;
            o.x = f2bf(acc[i][0] * s);
            o.y = f2bf(acc[i][1] * s);
            *(ushort2*)&out[r * DD + c0 + jc * 2] = o;
        }
    }
}

// out[i] = maybe_relu( dinv[i] * sum_{p in row i} hs[col[p]] + bias )
// hs is bf16 [N,128]; one wave per node, lane = 2 dims (one dword gather/row).
template <int RELU, int OUTF32>
__global__ __launch_bounds__(256) void k_agg(const ushort* __restrict__ hs,
                                             const int* __restrict__ col,
                                             const int* __restrict__ rp,
                                             const float* __restrict__ dinv,
                                             const float* __restrict__ bias,
                                             void* __restrict__ outv) {
    int w = threadIdx.x >> 6, lane = threadIdx.x & 63;
    int i = blockIdx.x * 4 + w;
    if (i >= NN) return;
    int p0 = rp[i], p1 = rp[i + 1];
    int d = lane * 2;
    float a0 = 0.f, a1 = 0.f, b0 = 0.f, b1 = 0.f;
    float c0f = 0.f, c1f = 0.f, e0 = 0.f, e1 = 0.f;
    int p = p0;
    for (; p + 4 <= p1; p += 4) {
        int c0 = col[p], c1 = col[p + 1], c2 = col[p + 2], c3 = col[p + 3];
        uint v0 = *(const uint*)(hs + (size_t)c0 * DD + d);
        uint v1 = *(const uint*)(hs + (size_t)c1 * DD + d);
        uint v2 = *(const uint*)(hs + (size_t)c2 * DD + d);
        uint v3 = *(const uint*)(hs + (size_t)c3 * DD + d);
        a0 += bf_lo(v0); a1 += bf_hi(v0);
        b0 += bf_lo(v1); b1 += bf_hi(v1);
        c0f += bf_lo(v2); c1f += bf_hi(v2);
        e0 += bf_lo(v3); e1 += bf_hi(v3);
    }
    for (; p < p1; ++p) {
        uint v = *(const uint*)(hs + (size_t)col[p] * DD + d);
        a0 += bf_lo(v); a1 += bf_hi(v);
    }
    float ax = (a0 + b0) + (c0f + e0);
    float ay = (a1 + b1) + (c1f + e1);
    float s = dinv[i];
    float2 bb = *(const float2*)(bias + d);
    float ox = fmaf(s, ax, bb.x), oy = fmaf(s, ay, bb.y);
    if (RELU) { ox = fmaxf(ox, 0.f); oy = fmaxf(oy, 0.f); }
    if (OUTF32) {
        *(float2*)((float*)outv + (size_t)i * DD + d) = make_float2(ox, oy);
    } else {
        ushort2 o; o.x = f2bf(ox); o.y = f2bf(oy);
        *(ushort2*)((ushort*)outv + (size_t)i * DD + d) = o;
    }
}

// batch sorted: run-length accumulate per 128-node chunk
__global__ void k_pool(const float* __restrict__ h, const int* __restrict__ batch,
                       float* __restrict__ sums, float* __restrict__ cnt) {
    int d = threadIdx.x;  // 0..127
    int start = blockIdx.x * 128;
    if (start >= NN) return;
    int end = min(start + 128, NN);
    float acc = 0.f, c = 0.f;
    int g = batch[start];
    for (int i = start; i < end; ++i) {
        int gi = batch[i];
        if (gi != g) {
            atomicAdd(&sums[g * DD + d], acc);
            if (d == 0) atomicAdd(&cnt[g], c);
            acc = 0.f; c = 0.f; g = gi;
        }
        acc += h[(size_t)i * DD + d];
        c += 1.f;
    }
    atomicAdd(&sums[g * DD + d], acc);
    if (d == 0) atomicAdd(&cnt[g], c);
}

__global__ void k_final(const float* __restrict__ sums, const float* __restrict__ cnt,
                        float* __restrict__ out) {
    int i = blockIdx.x * 256 + threadIdx.x;  // < NG*DD = 8192
    int g = i >> 7;
    out[i] = sums[i] / fmaxf(cnt[g], 1.f);
}

// ---------------- launch ----------------

extern "C" void kernel_launch(void* const* d_in, const int* in_sizes, int n_in,
                              void* d_out, int out_size, void* d_ws, size_t ws_size,
                              hipStream_t stream) {
    (void)in_sizes; (void)n_in; (void)out_size; (void)ws_size;
    const float* x  = (const float*)d_in[0];
    const int*   ei = (const int*)d_in[1];
    const int*   bt = (const int*)d_in[2];
    const float* W1 = (const float*)d_in[3];
    const float* b1 = (const float*)d_in[4];
    const float* W2 = (const float*)d_in[5];
    const float* b2 = (const float*)d_in[6];
    const float* W3 = (const float*)d_in[7];
    const float* b3 = (const float*)d_in[8];
    float* out = (float*)d_out;
    char* ws = (char*)d_ws;

    size_t o = 0;
    auto alloc = [&](size_t bytes) { size_t r = o; o = (o + bytes + 511) & ~(size_t)511; return r; };
    int*    deg  = (int*)(ws + alloc((size_t)NN * 4));
    int*    fill = (int*)(ws + alloc((size_t)NN * 4));
    float*  dinv = (float*)(ws + alloc((size_t)NN * 4));
    int*    rp   = (int*)(ws + alloc((size_t)(NN + 1) * 4));
    int*    bs   = (int*)(ws + alloc(256 * 4));
    int*    col  = (int*)(ws + alloc((size_t)(NE + NN) * 4));
    ushort* hsT  = (ushort*)(ws + alloc((size_t)NN * DD * 2));  // GEMM output tables (bf16)
    ushort* hsA  = (ushort*)(ws + alloc((size_t)NN * DD * 2));  // agg outputs (bf16)
    float*  F    = (float*)(ws + alloc((size_t)NN * DD * 4));   // final agg output (fp32)
    float*  pool = (float*)(ws + alloc((size_t)(NG * DD + NG) * 4));
    float*  cnt  = pool + NG * DD;

    const int* srcv = ei;        // edge_index[0]
    const int* dstv = ei + NE;   // edge_index[1]

    hipMemsetAsync(pool, 0, (size_t)(NG * DD + NG) * 4, stream);

    k_init<<<196, 256, 0, stream>>>(deg, fill);
    k_hist<<<(NE + 255) / 256, 256, 0, stream>>>(dstv, deg);
    k_scan1<<<196, 256, 0, stream>>>(deg, dinv, rp, bs);
    k_scan2<<<1, 256, 0, stream>>>(bs, 196);
    k_scan3<<<196, 256, 0, stream>>>(rp, bs);
    k_scatter<<<(NE + NN + 255) / 256, 256, 0, stream>>>(srcv, dstv, rp, fill, col);

    dim3 gg(782, 2);
    k_gemm<0><<<gg, 256, 0, stream>>>(x,   W1, dinv, hsT);
    k_agg<1, 0><<<12500, 256, 0, stream>>>(hsT, col, rp, dinv, b1, hsA);
    k_gemm<1><<<gg, 256, 0, stream>>>(hsA, W2, dinv, hsT);
    k_agg<1, 0><<<12500, 256, 0, stream>>>(hsT, col, rp, dinv, b2, hsA);
    k_gemm<1><<<gg, 256, 0, stream>>>(hsA, W3, dinv, hsT);
    k_agg<0, 1><<<12500, 256, 0, stream>>>(hsT, col, rp, dinv, b3, F);

    k_pool<<<(NN + 127) / 128, 128, 0, stream>>>(F, bt, pool, cnt);
    k_final<<<(NG * DD) / 256, 256, 0, stream>>>(pool, cnt, out);
}

// Round 3
// 330.732 us; speedup vs baseline: 1.4017x; 1.2281x over previous
//
#include <hip/hip_runtime.h>

#define NN 50000
#define NE 600000
#define DD 128
#define NG 64

typedef unsigned int uint;
typedef unsigned short ushort;
typedef __attribute__((ext_vector_type(8))) short short8;
typedef __attribute__((ext_vector_type(4))) float f4;

// ---------------- bf16 helpers ----------------

__device__ __forceinline__ float bf_lo(uint v) { return __uint_as_float(v << 16); }
__device__ __forceinline__ float bf_hi(uint v) { return __uint_as_float(v & 0xffff0000u); }
__device__ __forceinline__ float bf2f(ushort h) { return __uint_as_float((uint)h << 16); }
__device__ __forceinline__ ushort f2bf(float f) {
    uint u = __float_as_uint(f);
    uint r = (u + 0x7fffu + ((u >> 16) & 1u)) >> 16;   // round-nearest-even
    return (ushort)r;
}

// ---------------- setup kernels ----------------

__global__ void k_init(int* deg, int* fill) {
    int i = blockIdx.x * 256 + threadIdx.x;
    if (i < NN) { deg[i] = 1; fill[i] = 0; }   // deg starts at 1 (self-loop)
}

__global__ void k_hist(const int* __restrict__ dstv, int* __restrict__ deg) {
    int e = blockIdx.x * 256 + threadIdx.x;
    if (e < NE) atomicAdd(&deg[dstv[e]], 1);
}

__global__ void k_scan1(const int* __restrict__ deg, float* __restrict__ dinv,
                        int* __restrict__ rp, int* __restrict__ bsum) {
    __shared__ int s[256];
    int t = threadIdx.x, i = blockIdx.x * 256 + t;
    int v = (i < NN) ? deg[i] : 0;
    if (i < NN) dinv[i] = rsqrtf((float)v);
    s[t] = v; __syncthreads();
    for (int off = 1; off < 256; off <<= 1) {
        int x = (t >= off) ? s[t - off] : 0;
        __syncthreads();
        s[t] += x;
        __syncthreads();
    }
    if (i < NN) rp[i] = s[t] - v;           // exclusive
    if (t == 255) bsum[blockIdx.x] = s[255];
}

__global__ void k_scan2(int* bs, int nb) {
    __shared__ int s[256];
    int t = threadIdx.x;
    int v = (t < nb) ? bs[t] : 0;
    s[t] = v; __syncthreads();
    for (int off = 1; off < 256; off <<= 1) {
        int x = (t >= off) ? s[t - off] : 0;
        __syncthreads();
        s[t] += x;
        __syncthreads();
    }
    if (t < nb) bs[t] = s[t] - v;
}

__global__ void k_scan3(int* rp, const int* bs) {
    int i = blockIdx.x * 256 + threadIdx.x;
    if (i < NN) rp[i] += bs[i >> 8];
    if (i == 0) rp[NN] = NE + NN;
}

__global__ void k_scatter(const int* __restrict__ srcv, const int* __restrict__ dstv,
                          const int* __restrict__ rp, int* __restrict__ fill,
                          int* __restrict__ col) {
    int t = blockIdx.x * 256 + threadIdx.x;
    if (t < NE) {
        int s = srcv[t], d = dstv[t];
        int pos = rp[d] + atomicAdd(&fill[d], 1);
        col[pos] = s;
    } else if (t < NE + NN) {
        int i = t - NE;
        int pos = rp[i] + atomicAdd(&fill[i], 1);
        col[pos] = i;
    }
}

// Pack W [128x128 f32] into MFMA B-fragment layout, split bf16 hi + lo.
// frag index g = (nt*4 + kk)*64 + lane; element j: k = kk*32 + (lane>>4)*8 + j,
// n = nt*16 + (lane&15). Output: base[g*8+j] = hi, base[16384 + g*8+j] = lo.
__global__ void k_wpack(const float* __restrict__ W1, const float* __restrict__ W2,
                        const float* __restrict__ W3, short* __restrict__ out) {
    const float* W = (blockIdx.y == 0) ? W1 : (blockIdx.y == 1) ? W2 : W3;
    short* base = out + (size_t)blockIdx.y * 32768;
    int g = blockIdx.x * 256 + threadIdx.x;   // 0..2047
    int nt = g >> 8, kk = (g >> 6) & 3, lane = g & 63;
    int k0 = kk * 32 + (lane >> 4) * 8;
    int n = nt * 16 + (lane & 15);
    #pragma unroll
    for (int j = 0; j < 8; ++j) {
        float w = W[(size_t)(k0 + j) * DD + n];
        ushort h = f2bf(w);
        float r = w - bf2f(h);
        base[g * 8 + j] = (short)h;
        base[16384 + g * 8 + j] = (short)f2bf(r);
    }
}

// ---------------- MFMA GEMM ----------------
// out[r][c] = bf16( (X[r][:] @ W[:][c]) * dinv[r] )
// Split-precision: W = Whi + Wlo (bf16 pair); layer 1 also splits fp32 X.
// Block 256 (4 waves); wave handles 2 strips x 16 rows = 32 rows, full N=128.
template <int INF32>
__global__ __launch_bounds__(256) void k_gemm_mfma(const void* __restrict__ Xv,
                                                   const short* __restrict__ wpk,
                                                   const float* __restrict__ dinv,
                                                   ushort* __restrict__ out) {
    __shared__ short lds[32768];   // [0..16384) Whi frags, [16384..32768) Wlo frags
    const int t = threadIdx.x;
    #pragma unroll
    for (int m = 0; m < 16; ++m) {
        int idx = (m * 256 + t) * 8;
        *(float4*)&lds[idx] = *(const float4*)&wpk[idx];
    }

    const int wv = t >> 6, lane = t & 63;
    const int quad = lane >> 4, l16 = lane & 15;
    const int r0 = blockIdx.x * 128 + wv * 32;

    short8 aH[2][4], aL[2][4];
    #pragma unroll
    for (int s = 0; s < 2; ++s) {
        int row = r0 + s * 16 + l16;
        #pragma unroll
        for (int kk = 0; kk < 4; ++kk) {
            int koff = kk * 32 + quad * 8;
            if (INF32) {
                float4 x0 = make_float4(0.f, 0.f, 0.f, 0.f), x1 = x0;
                if (row < NN) {
                    const float* p = (const float*)Xv + (size_t)row * DD + koff;
                    x0 = *(const float4*)p; x1 = *(const float4*)(p + 4);
                }
                float xs[8] = {x0.x, x0.y, x0.z, x0.w, x1.x, x1.y, x1.z, x1.w};
                short8 h, l;
                #pragma unroll
                for (int j = 0; j < 8; ++j) {
                    ushort hb = f2bf(xs[j]);
                    h[j] = (short)hb;
                    l[j] = (short)f2bf(xs[j] - bf2f(hb));
                }
                aH[s][kk] = h; aL[s][kk] = l;
            } else {
                short8 h = {0, 0, 0, 0, 0, 0, 0, 0};
                if (row < NN)
                    h = *(const short8*)((const ushort*)Xv + (size_t)row * DD + koff);
                aH[s][kk] = h;
            }
        }
    }
    __syncthreads();

    float dv[2][4];
    #pragma unroll
    for (int s = 0; s < 2; ++s)
        #pragma unroll
        for (int i = 0; i < 4; ++i) {
            int row = r0 + s * 16 + quad * 4 + i;
            dv[s][i] = (row < NN) ? dinv[row] : 0.f;
        }

    #pragma unroll
    for (int nt = 0; nt < 8; ++nt) {
        f4 acc0 = {0.f, 0.f, 0.f, 0.f}, acc1 = acc0;
        #pragma unroll
        for (int kk = 0; kk < 4; ++kk) {
            int fi = ((nt * 4 + kk) * 64 + lane) * 8;
            short8 bh = *(const short8*)&lds[fi];
            short8 bl = *(const short8*)&lds[16384 + fi];
            acc0 = __builtin_amdgcn_mfma_f32_16x16x32_bf16(aH[0][kk], bh, acc0, 0, 0, 0);
            acc0 = __builtin_amdgcn_mfma_f32_16x16x32_bf16(aH[0][kk], bl, acc0, 0, 0, 0);
            acc1 = __builtin_amdgcn_mfma_f32_16x16x32_bf16(aH[1][kk], bh, acc1, 0, 0, 0);
            acc1 = __builtin_amdgcn_mfma_f32_16x16x32_bf16(aH[1][kk], bl, acc1, 0, 0, 0);
            if (INF32) {
                acc0 = __builtin_amdgcn_mfma_f32_16x16x32_bf16(aL[0][kk], bh, acc0, 0, 0, 0);
                acc1 = __builtin_amdgcn_mfma_f32_16x16x32_bf16(aL[1][kk], bh, acc1, 0, 0, 0);
            }
        }
        #pragma unroll
        for (int i = 0; i < 4; ++i) {
            int row0w = r0 + quad * 4 + i;
            if (row0w < NN)
                out[(size_t)row0w * DD + nt * 16 + l16] = f2bf(acc0[i] * dv[0][i]);
            int row1w = r0 + 16 + quad * 4 + i;
            if (row1w < NN)
                out[(size_t)row1w * DD + nt * 16 + l16] = f2bf(acc1[i] * dv[1][i]);
        }
    }
}

// out[i] = maybe_relu( dinv[i] * sum_{p in row i} hs[col[p]] + bias )
template <int RELU, int OUTF32>
__global__ __launch_bounds__(256) void k_agg(const ushort* __restrict__ hs,
                                             const int* __restrict__ col,
                                             const int* __restrict__ rp,
                                             const float* __restrict__ dinv,
                                             const float* __restrict__ bias,
                                             void* __restrict__ outv) {
    int w = threadIdx.x >> 6, lane = threadIdx.x & 63;
    int i = blockIdx.x * 4 + w;
    if (i >= NN) return;
    int p0 = rp[i], p1 = rp[i + 1];
    int d = lane * 2;
    float a0 = 0.f, a1 = 0.f, b0 = 0.f, b1 = 0.f;
    float c0f = 0.f, c1f = 0.f, e0 = 0.f, e1 = 0.f;
    int p = p0;
    for (; p + 4 <= p1; p += 4) {
        int c0 = col[p], c1 = col[p + 1], c2 = col[p + 2], c3 = col[p + 3];
        uint v0 = *(const uint*)(hs + (size_t)c0 * DD + d);
        uint v1 = *(const uint*)(hs + (size_t)c1 * DD + d);
        uint v2 = *(const uint*)(hs + (size_t)c2 * DD + d);
        uint v3 = *(const uint*)(hs + (size_t)c3 * DD + d);
        a0 += bf_lo(v0); a1 += bf_hi(v0);
        b0 += bf_lo(v1); b1 += bf_hi(v1);
        c0f += bf_lo(v2); c1f += bf_hi(v2);
        e0 += bf_lo(v3); e1 += bf_hi(v3);
    }
    for (; p < p1; ++p) {
        uint v = *(const uint*)(hs + (size_t)col[p] * DD + d);
        a0 += bf_lo(v); a1 += bf_hi(v);
    }
    float ax = (a0 + b0) + (c0f + e0);
    float ay = (a1 + b1) + (c1f + e1);
    float s = dinv[i];
    float2 bb = *(const float2*)(bias + d);
    float ox = fmaf(s, ax, bb.x), oy = fmaf(s, ay, bb.y);
    if (RELU) { ox = fmaxf(ox, 0.f); oy = fmaxf(oy, 0.f); }
    if (OUTF32) {
        *(float2*)((float*)outv + (size_t)i * DD + d) = make_float2(ox, oy);
    } else {
        ushort2 o; o.x = f2bf(ox); o.y = f2bf(oy);
        *(ushort2*)((ushort*)outv + (size_t)i * DD + d) = o;
    }
}

// batch sorted: run-length accumulate per 128-node chunk
__global__ void k_pool(const float* __restrict__ h, const int* __restrict__ batch,
                       float* __restrict__ sums, float* __restrict__ cnt) {
    int d = threadIdx.x;  // 0..127
    int start = blockIdx.x * 128;
    if (start >= NN) return;
    int end = min(start + 128, NN);
    float acc = 0.f, c = 0.f;
    int g = batch[start];
    for (int i = start; i < end; ++i) {
        int gi = batch[i];
        if (gi != g) {
            atomicAdd(&sums[g * DD + d], acc);
            if (d == 0) atomicAdd(&cnt[g], c);
            acc = 0.f; c = 0.f; g = gi;
        }
        acc += h[(size_t)i * DD + d];
        c += 1.f;
    }
    atomicAdd(&sums[g * DD + d], acc);
    if (d == 0) atomicAdd(&cnt[g], c);
}

__global__ void k_final(const float* __restrict__ sums, const float* __restrict__ cnt,
                        float* __restrict__ out) {
    int i = blockIdx.x * 256 + threadIdx.x;  // < NG*DD = 8192
    int g = i >> 7;
    out[i] = sums[i] / fmaxf(cnt[g], 1.f);
}

// ---------------- launch ----------------

extern "C" void kernel_launch(void* const* d_in, const int* in_sizes, int n_in,
                              void* d_out, int out_size, void* d_ws, size_t ws_size,
                              hipStream_t stream) {
    (void)in_sizes; (void)n_in; (void)out_size; (void)ws_size;
    const float* x  = (const float*)d_in[0];
    const int*   ei = (const int*)d_in[1];
    const int*   bt = (const int*)d_in[2];
    const float* W1 = (const float*)d_in[3];
    const float* b1 = (const float*)d_in[4];
    const float* W2 = (const float*)d_in[5];
    const float* b2 = (const float*)d_in[6];
    const float* W3 = (const float*)d_in[7];
    const float* b3 = (const float*)d_in[8];
    float* out = (float*)d_out;
    char* ws = (char*)d_ws;

    size_t o = 0;
    auto alloc = [&](size_t bytes) { size_t r = o; o = (o + bytes + 511) & ~(size_t)511; return r; };
    int*    deg  = (int*)(ws + alloc((size_t)NN * 4));
    int*    fill = (int*)(ws + alloc((size_t)NN * 4));
    float*  dinv = (float*)(ws + alloc((size_t)NN * 4));
    int*    rp   = (int*)(ws + alloc((size_t)(NN + 1) * 4));
    int*    bs   = (int*)(ws + alloc(256 * 4));
    int*    col  = (int*)(ws + alloc((size_t)(NE + NN) * 4));
    short*  wpk  = (short*)(ws + alloc((size_t)3 * 32768 * 2));  // 3 x (hi|lo) frag-packed W
    ushort* hsT  = (ushort*)(ws + alloc((size_t)NN * DD * 2));   // GEMM output tables (bf16)
    ushort* hsA  = (ushort*)(ws + alloc((size_t)NN * DD * 2));   // agg outputs (bf16)
    float*  F    = (float*)(ws + alloc((size_t)NN * DD * 4));    // final agg output (fp32)
    float*  pool = (float*)(ws + alloc((size_t)(NG * DD + NG) * 4));
    float*  cnt  = pool + NG * DD;

    const int* srcv = ei;        // edge_index[0]
    const int* dstv = ei + NE;   // edge_index[1]

    hipMemsetAsync(pool, 0, (size_t)(NG * DD + NG) * 4, stream);

    k_init<<<196, 256, 0, stream>>>(deg, fill);
    k_hist<<<(NE + 255) / 256, 256, 0, stream>>>(dstv, deg);
    k_scan1<<<196, 256, 0, stream>>>(deg, dinv, rp, bs);
    k_scan2<<<1, 256, 0, stream>>>(bs, 196);
    k_scan3<<<196, 256, 0, stream>>>(rp, bs);
    k_scatter<<<(NE + NN + 255) / 256, 256, 0, stream>>>(srcv, dstv, rp, fill, col);
    k_wpack<<<dim3(8, 3), 256, 0, stream>>>(W1, W2, W3, wpk);

    const int gG = (NN + 127) / 128;   // 391
    k_gemm_mfma<1><<<gG, 256, 0, stream>>>(x, wpk, dinv, hsT);
    k_agg<1, 0><<<12500, 256, 0, stream>>>(hsT, col, rp, dinv, b1, hsA);
    k_gemm_mfma<0><<<gG, 256, 0, stream>>>(hsA, wpk + 32768, dinv, hsT);
    k_agg<1, 0><<<12500, 256, 0, stream>>>(hsT, col, rp, dinv, b2, hsA);
    k_gemm_mfma<0><<<gG, 256, 0, stream>>>(hsA, wpk + 65536, dinv, hsT);
    k_agg<0, 1><<<12500, 256, 0, stream>>>(hsT, col, rp, dinv, b3, F);

    k_pool<<<(NN + 127) / 128, 128, 0, stream>>>(F, bt, pool, cnt);
    k_final<<<(NG * DD) / 256, 256, 0, stream>>>(pool, cnt, out);
}